// Round 1
// baseline (652.010 us; speedup 1.0000x reference)
//
#include <hip/hip_runtime.h>
#include <hip/hip_bf16.h>

// Problem constants (from reference):
// R=2048 rois, C=81 classes, M=28 mask size, G=100 gt, H=W=512, NUM_POS=512
#define RR 2048
#define CC 81
#define MM 28
#define GG 100
#define HH 512
#define WW 512

// ---------------- init: zero outputs + workspace accumulators ----------------
__global__ void init_kernel(float* out, float* ws) {
    int t = threadIdx.x;
    // out: 102 floats; ws: 2*GG floats (seg_sum, cnt)
    for (int i = t; i < 102; i += blockDim.x) out[i] = 0.0f;
    for (int i = t; i < 2 * GG; i += blockDim.x) ws[i] = 0.0f;
}

// ---------------- cls loss: one wave (64 lanes) per row ----------------
__global__ void cls_kernel(const float* __restrict__ logits,
                           const int* __restrict__ label,
                           float* __restrict__ out) {
    int wave = threadIdx.x >> 6;          // 4 waves per block
    int lane = threadIdx.x & 63;
    int row = blockIdx.x * 4 + wave;
    if (row >= RR) return;

    const float* rowp = logits + (size_t)row * CC;
    // each lane covers c = lane and c = lane + 64 (only lanes < CC-64 have 2nd)
    float v0 = (lane < CC) ? rowp[lane] : -1e30f;
    float v1 = (lane + 64 < CC) ? rowp[lane + 64] : -1e30f;
    float m = fmaxf(v0, v1);
    #pragma unroll
    for (int off = 32; off > 0; off >>= 1) m = fmaxf(m, __shfl_down(m, off));
    m = __shfl(m, 0);

    float s = 0.0f;
    if (lane < CC) s += __expf(v0 - m);
    if (lane + 64 < CC) s += __expf(v1 - m);
    #pragma unroll
    for (int off = 32; off > 0; off >>= 1) s += __shfl_down(s, off);

    if (lane == 0) {
        float lse = m + __logf(s);
        float v = rowp[label[row]];
        // -logp / N
        atomicAdd(out + 0, (lse - v) * (1.0f / (float)RR));
    }
}

// ---------------- box loss: smooth L1 over NUM_POS*4 elems ----------------
__global__ void box_kernel(const float* __restrict__ box_reg,   // [R, 4*C]
                           const float* __restrict__ reg_tgt,   // [NUM_POS, 4]
                           const int* __restrict__ label,
                           const int* __restrict__ num_pos_p,
                           float* __restrict__ out) {
    int num_pos = *num_pos_p;
    int t = blockIdx.x * blockDim.x + threadIdx.x; // up to 512*4 = 2048
    float l = 0.0f;
    int i = t >> 2, j = t & 3;
    if (i < num_pos) {
        float pred = box_reg[(size_t)i * (4 * CC) + label[i] * 4 + j];
        float d = fabsf(pred - reg_tgt[i * 4 + j]);
        l = (d < 1.0f) ? 0.5f * d * d : d - 0.5f;
    }
    // block reduce
    #pragma unroll
    for (int off = 32; off > 0; off >>= 1) l += __shfl_down(l, off);
    __shared__ float sm[8];
    int lane = threadIdx.x & 63, wid = threadIdx.x >> 6;
    if (lane == 0) sm[wid] = l;
    __syncthreads();
    if (threadIdx.x == 0) {
        float tot = 0.0f;
        int nw = blockDim.x >> 6;
        for (int k = 0; k < nw; k++) tot += sm[k];
        atomicAdd(out + 1, tot * (1.0f / (float)RR));
    }
}

// ---------------- mask loss: one block per roi ----------------
__global__ void mask_kernel(const float* __restrict__ mask_logit, // [R,C,M,M]
                            const float* __restrict__ proposal,   // [R,4]
                            const float* __restrict__ gt_mask,    // [G,H,W]
                            const int* __restrict__ matched_idx,  // [R]
                            const int* __restrict__ label,        // [R]
                            float* __restrict__ seg_sum,          // [G]
                            float* __restrict__ cnt) {            // [G]
    int r = blockIdx.x;
    int t = threadIdx.x;

    float x1 = proposal[r * 4 + 0];
    float y1 = proposal[r * 4 + 1];
    float x2 = proposal[r * 4 + 2];
    float y2 = proposal[r * 4 + 3];
    int m_idx = matched_idx[r];
    int lbl = label[r];

    const float* sel = mask_logit + ((size_t)r * CC + lbl) * (MM * MM);
    const float* fm = gt_mask + (size_t)m_idx * (HH * WW);

    float bw = x2 - x1, bh = y2 - y1;

    float acc = 0.0f;
    for (int p = t; p < MM * MM; p += blockDim.x) {
        int py = p / MM, px = p % MM;
        float gx = x1 + ((px + 0.5f) / (float)MM) * bw;
        float gy = y1 + ((py + 0.5f) / (float)MM) * bh;
        bool valid = (gx > -1.0f) && (gx < (float)WW) && (gy > -1.0f) && (gy < (float)HH);
        float xc = fminf(fmaxf(gx, 0.0f), (float)(WW - 1));
        float yc = fminf(fmaxf(gy, 0.0f), (float)(HH - 1));
        int x0 = (int)floorf(xc);
        int y0 = (int)floorf(yc);
        int x1i = min(x0 + 1, WW - 1);
        int y1i = min(y0 + 1, HH - 1);
        float lx = xc - (float)x0;
        float ly = yc - (float)y0;
        float v00 = fm[y0 * WW + x0];
        float v01 = fm[y0 * WW + x1i];
        float v10 = fm[y1i * WW + x0];
        float v11 = fm[y1i * WW + x1i];
        float val = v00 * (1.0f - ly) * (1.0f - lx) + v01 * (1.0f - ly) * lx +
                    v10 * ly * (1.0f - lx) + v11 * ly * lx;
        float tgt = valid ? val : 0.0f;

        float s = sel[p];
        float bce = fmaxf(s, 0.0f) - s * tgt + log1pf(__expf(-fabsf(s)));
        acc += bce;
    }

    // block reduce
    #pragma unroll
    for (int off = 32; off > 0; off >>= 1) acc += __shfl_down(acc, off);
    __shared__ float sm[8];
    int lane = t & 63, wid = t >> 6;
    if (lane == 0) sm[wid] = acc;
    __syncthreads();
    if (t == 0) {
        float tot = 0.0f;
        int nw = blockDim.x >> 6;
        for (int k = 0; k < nw; k++) tot += sm[k];
        float per_roi = tot * (1.0f / (float)(MM * MM));
        atomicAdd(seg_sum + m_idx, per_roi);
        atomicAdd(cnt + m_idx, 1.0f);
    }
}

// ---------------- finalize per-gt ----------------
__global__ void fin_kernel(const float* __restrict__ seg_sum,
                           const float* __restrict__ cnt,
                           float* __restrict__ out) {
    int g = threadIdx.x + blockIdx.x * blockDim.x;
    if (g < GG) {
        float c = cnt[g];
        out[2 + g] = (c > 0.0f) ? seg_sum[g] / fmaxf(c, 1.0f) : 0.0f;
    }
}

extern "C" void kernel_launch(void* const* d_in, const int* in_sizes, int n_in,
                              void* d_out, int out_size, void* d_ws, size_t ws_size,
                              hipStream_t stream) {
    const float* class_logit    = (const float*)d_in[0];
    const float* box_regression = (const float*)d_in[1];
    const float* regression_tgt = (const float*)d_in[2];
    const float* mask_logit     = (const float*)d_in[3];
    const float* proposal       = (const float*)d_in[4];
    const float* gt_mask        = (const float*)d_in[5];
    const int*   matched_idx    = (const int*)d_in[6];
    const int*   label          = (const int*)d_in[7];
    const int*   num_pos        = (const int*)d_in[8];

    float* out = (float*)d_out;
    float* seg_sum = (float*)d_ws;        // GG floats
    float* cnt = seg_sum + GG;            // GG floats

    init_kernel<<<1, 256, 0, stream>>>(out, seg_sum);

    cls_kernel<<<RR / 4, 256, 0, stream>>>(class_logit, label, out);

    box_kernel<<<(512 * 4 + 255) / 256, 256, 0, stream>>>(
        box_regression, regression_tgt, label, num_pos, out);

    mask_kernel<<<RR, 256, 0, stream>>>(mask_logit, proposal, gt_mask,
                                        matched_idx, label, seg_sum, cnt);

    fin_kernel<<<1, 128, 0, stream>>>(seg_sum, cnt, out);
}

// Round 2
// 645.965 us; speedup vs baseline: 1.0094x; 1.0094x over previous
//
#include <hip/hip_runtime.h>
#include <hip/hip_bf16.h>

// Problem constants (from reference):
// R=2048 rois, C=81 classes, M=28 mask size, G=100 gt, H=W=512, NUM_POS=512
#define RR 2048
#define CC 81
#define MM 28
#define GG 100
#define HH 512
#define WW 512

// ---------------- init: zero outputs + workspace accumulators ----------------
__global__ void init_kernel(float* out, float* ws) {
    int t = threadIdx.x;
    // out: 102 floats; ws: 2*GG floats (seg_sum, cnt)
    for (int i = t; i < 102; i += blockDim.x) out[i] = 0.0f;
    for (int i = t; i < 2 * GG; i += blockDim.x) ws[i] = 0.0f;
}

// ---------------- fused: one wave per roi does box + cls + mask ----------------
__global__ __launch_bounds__(256) void fused_kernel(
    const float* __restrict__ class_logit,  // [R,C]
    const float* __restrict__ box_reg,      // [R,4C]
    const float* __restrict__ reg_tgt,      // [NUM_POS,4]
    const float* __restrict__ mask_logit,   // [R,C,M,M]
    const float* __restrict__ proposal,     // [R,4]
    const float* __restrict__ gt_mask,      // [G,H,W]
    const int* __restrict__ matched_idx,    // [R]
    const int* __restrict__ label,          // [R]
    const int* __restrict__ num_pos_p,
    float* __restrict__ out,                // [102]
    float* __restrict__ seg_sum,            // [G]
    float* __restrict__ cnt) {              // [G]
    int lane = threadIdx.x & 63;
    int r = blockIdx.x * 4 + (threadIdx.x >> 6);   // wave id == roi id, [0,2048)

    int lbl = label[r];
    int m_idx = matched_idx[r];

    // ---- box loss: lanes 0..3 handle the 4 coords of roi r (if r < num_pos) ----
    int num_pos = *num_pos_p;
    if (r < num_pos) {
        float bl = 0.0f;
        if (lane < 4) {
            float pred = box_reg[(size_t)r * (4 * CC) + lbl * 4 + lane];
            float d = fabsf(pred - reg_tgt[r * 4 + lane]);
            bl = (d < 1.0f) ? 0.5f * d * d : d - 0.5f;
        }
        bl += __shfl_down(bl, 2);
        bl += __shfl_down(bl, 1);
        if (lane == 0) atomicAdd(out + 1, bl * (1.0f / (float)RR));
    }

    // ---- cls loss: wave log-softmax over C=81 ----
    {
        const float* rowp = class_logit + (size_t)r * CC;
        float v0 = (lane < CC) ? rowp[lane] : -1e30f;
        float v1 = (lane + 64 < CC) ? rowp[lane + 64] : -1e30f;
        float m = fmaxf(v0, v1);
        #pragma unroll
        for (int off = 32; off > 0; off >>= 1) m = fmaxf(m, __shfl_down(m, off));
        m = __shfl(m, 0);
        float s = 0.0f;
        if (lane < CC) s += __expf(v0 - m);
        if (lane + 64 < CC) s += __expf(v1 - m);
        #pragma unroll
        for (int off = 32; off > 0; off >>= 1) s += __shfl_down(s, off);
        if (lane == 0) {
            float lse = m + __logf(s);
            atomicAdd(out + 0, (lse - rowp[lbl]) * (1.0f / (float)RR));
        }
    }

    // ---- mask loss: roi-align (1 sample/bin) + BCE-with-logits, wave-reduced ----
    {
        float x1 = proposal[r * 4 + 0];
        float y1 = proposal[r * 4 + 1];
        float x2 = proposal[r * 4 + 2];
        float y2 = proposal[r * 4 + 3];
        float bw = x2 - x1, bh = y2 - y1;

        // (r*CC+lbl)*784 floats = multiple of 16B -> float4-aligned
        const float4* sel4 = (const float4*)(mask_logit + ((size_t)r * CC + lbl) * (MM * MM));
        const float* fm = gt_mask + (size_t)m_idx * (HH * WW);

        float acc = 0.0f;
        for (int i4 = lane; i4 < (MM * MM) / 4; i4 += 64) {   // 196 float4s
            float4 sv = sel4[i4];
            float svv[4] = {sv.x, sv.y, sv.z, sv.w};
            int pbase = i4 * 4;
            #pragma unroll
            for (int j = 0; j < 4; j++) {
                int p = pbase + j;
                int py = p / MM, px = p - py * MM;
                float gx = x1 + ((px + 0.5f) / (float)MM) * bw;
                float gy = y1 + ((py + 0.5f) / (float)MM) * bh;
                bool valid = (gx > -1.0f) && (gx < (float)WW) && (gy > -1.0f) && (gy < (float)HH);
                float xc = fminf(fmaxf(gx, 0.0f), (float)(WW - 1));
                float yc = fminf(fmaxf(gy, 0.0f), (float)(HH - 1));
                int x0 = (int)floorf(xc);
                int y0 = (int)floorf(yc);
                int x1i = min(x0 + 1, WW - 1);
                int y1i = min(y0 + 1, HH - 1);
                float lx = xc - (float)x0;
                float ly = yc - (float)y0;
                float v00 = fm[y0 * WW + x0];
                float v01 = fm[y0 * WW + x1i];
                float v10 = fm[y1i * WW + x0];
                float v11 = fm[y1i * WW + x1i];
                float val = v00 * (1.0f - ly) * (1.0f - lx) + v01 * (1.0f - ly) * lx +
                            v10 * ly * (1.0f - lx) + v11 * ly * lx;
                float tgt = valid ? val : 0.0f;
                float s = svv[j];
                acc += fmaxf(s, 0.0f) - s * tgt + log1pf(__expf(-fabsf(s)));
            }
        }
        #pragma unroll
        for (int off = 32; off > 0; off >>= 1) acc += __shfl_down(acc, off);
        if (lane == 0) {
            atomicAdd(seg_sum + m_idx, acc * (1.0f / (float)(MM * MM)));
            atomicAdd(cnt + m_idx, 1.0f);
        }
    }
}

// ---------------- finalize per-gt ----------------
__global__ void fin_kernel(const float* __restrict__ seg_sum,
                           const float* __restrict__ cnt,
                           float* __restrict__ out) {
    int g = threadIdx.x + blockIdx.x * blockDim.x;
    if (g < GG) {
        float c = cnt[g];
        out[2 + g] = (c > 0.0f) ? seg_sum[g] / fmaxf(c, 1.0f) : 0.0f;
    }
}

extern "C" void kernel_launch(void* const* d_in, const int* in_sizes, int n_in,
                              void* d_out, int out_size, void* d_ws, size_t ws_size,
                              hipStream_t stream) {
    const float* class_logit    = (const float*)d_in[0];
    const float* box_regression = (const float*)d_in[1];
    const float* regression_tgt = (const float*)d_in[2];
    const float* mask_logit     = (const float*)d_in[3];
    const float* proposal       = (const float*)d_in[4];
    const float* gt_mask        = (const float*)d_in[5];
    const int*   matched_idx    = (const int*)d_in[6];
    const int*   label          = (const int*)d_in[7];
    const int*   num_pos        = (const int*)d_in[8];

    float* out = (float*)d_out;
    float* seg_sum = (float*)d_ws;        // GG floats
    float* cnt = seg_sum + GG;            // GG floats

    init_kernel<<<1, 256, 0, stream>>>(out, seg_sum);

    fused_kernel<<<RR / 4, 256, 0, stream>>>(
        class_logit, box_regression, regression_tgt, mask_logit, proposal,
        gt_mask, matched_idx, label, num_pos, out, seg_sum, cnt);

    fin_kernel<<<1, 128, 0, stream>>>(seg_sum, cnt, out);
}